// Round 15
// baseline (137.865 us; speedup 1.0000x reference)
//
#include <hip/hip_runtime.h>
#include <hip/hip_fp16.h>
#include <math.h>

#define DFEAT 128
#define RSH 5            // log2(rows per range)
#define RSZ 32           // rows per range
#define MAXR 2048        // max ranges (N <= 65504)
#define NT  512          // threads per block
#define EPB 4096         // edges per bin chunk
#define CAP 2048         // gather collect capacity (range mean ~512)
typedef unsigned long long u64;
typedef unsigned int u32;
typedef unsigned short u16;
#define ENDK 0xFFFFFFFFFFFFFFFFULL

__device__ __forceinline__ void elu_store(const float* x, const float* w,
                                          __half* emb2, int i) {
    float4 xv = ((const float4*)x)[i];
    float4 wv = ((const float4*)w)[i & (DFEAT / 4 - 1)];
    float a, r0, r1, r2, r3;
    a = xv.x * wv.x; r0 = 2.0f * (a > 0.0f ? a : (__expf(a) - 1.0f));
    a = xv.y * wv.y; r1 = 2.0f * (a > 0.0f ? a : (__expf(a) - 1.0f));
    a = xv.z * wv.z; r2 = 2.0f * (a > 0.0f ? a : (__expf(a) - 1.0f));
    a = xv.w * wv.w; r3 = 2.0f * (a > 0.0f ? a : (__expf(a) - 1.0f));
    __half2 h01 = __floats2half2_rn(r0, r1);
    __half2 h23 = __floats2half2_rn(r2, r3);
    uint2 pk;
    pk.x = *(u32*)&h01;
    pk.y = *(u32*)&h23;
    ((uint2*)emb2)[i] = pk;
}

// K1: blocks [0,EB): chunk-local counting-sort of 4096 edges by range id
// (dst>>RSH). Zero global atomics: block c's sorted pairs land at
// pairs[c*EPB ...] (deterministic), per-(range,chunk) starts go to
// loff[r][c] (transposed: scattered column write here, coalesced row read
// in gather). Pair word: (row5<<16)|src16.
// blocks [EB,..): elu -> emb2 fp16.
__global__ __launch_bounds__(NT) void bin_elu_kernel(
        const float* __restrict__ x, const float* __restrict__ w,
        __half* __restrict__ emb2, int total4,
        const int* __restrict__ src, const int* __restrict__ dst, int E,
        u32* __restrict__ pairs, u32* __restrict__ loff,
        int EB, int NR) {
    if ((int)blockIdx.x < EB) {
        __shared__ u32 cnt[MAXR];      // 8 KB: counts -> starts -> cursors
        __shared__ u32 sb[NT];         // 2 KB: scan partials
        __shared__ u32 stage[EPB];     // 16 KB: sorted staging
        int tid = threadIdx.x;
        int c = blockIdx.x;
        for (int i = tid; i < MAXR; i += NT) cnt[i] = 0;
        __syncthreads();
        int base = c * EPB;
        int csz = E - base; if (csz > EPB) csz = EPB;
        // named per-edge state (rule #20)
        u32 k0=~0u,k1=~0u,k2=~0u,k3=~0u,k4=~0u,k5=~0u,k6=~0u,k7=~0u;
        u32 w0=0,w1=0,w2=0,w3=0,w4=0,w5=0,w6=0,w7=0;
#define BIN_LOAD(Q, K, W) { \
        int e = base + tid + Q * NT; \
        if (e < E) { \
            u32 d = (u32)dst[e]; \
            u32 s = (u32)src[e]; \
            u32 r = d >> RSH; if (r >= (u32)NR) r = (u32)NR - 1u; \
            atomicAdd(&cnt[r], 1u); \
            K = r; \
            W = ((d & (RSZ - 1u)) << 16) | (s & 0xFFFFu); \
        } }
        BIN_LOAD(0, k0, w0) BIN_LOAD(1, k1, w1) BIN_LOAD(2, k2, w2) BIN_LOAD(3, k3, w3)
        BIN_LOAD(4, k4, w4) BIN_LOAD(5, k5, w5) BIN_LOAD(6, k6, w6) BIN_LOAD(7, k7, w7)
#undef BIN_LOAD
        __syncthreads();
        // exclusive scan of cnt[0..MAXR), 4 elems/thread (zeros past NR harmless)
        u32 c0 = cnt[4 * tid], c1 = cnt[4 * tid + 1];
        u32 c2 = cnt[4 * tid + 2], c3 = cnt[4 * tid + 3];
        sb[tid] = c0 + c1 + c2 + c3;
        __syncthreads();
        for (int d = 1; d < NT; d <<= 1) {
            u32 o = (tid >= d) ? sb[tid - d] : 0u;
            __syncthreads();
            sb[tid] += o;
            __syncthreads();
        }
        u32 excl = sb[tid] - (c0 + c1 + c2 + c3);
        cnt[4 * tid]     = excl;
        cnt[4 * tid + 1] = excl + c0;
        cnt[4 * tid + 2] = excl + c0 + c1;
        cnt[4 * tid + 3] = excl + c0 + c1 + c2;
        __syncthreads();
        // write loff column c: starts per range, then row NR = chunk size
        for (int r = tid; r < NR; r += NT)
            loff[(size_t)r * EB + c] = cnt[r];
        if (tid == 0) loff[(size_t)NR * EB + c] = (u32)csz;
        __syncthreads();   // cnt reads done before cursor mutation
#define BIN_PLACE(K, W) if (K != ~0u) { \
        u32 p = atomicAdd(&cnt[K], 1u); \
        stage[p & (EPB - 1u)] = W; }
        BIN_PLACE(k0, w0) BIN_PLACE(k1, w1) BIN_PLACE(k2, w2) BIN_PLACE(k3, w3)
        BIN_PLACE(k4, w4) BIN_PLACE(k5, w5) BIN_PLACE(k6, w6) BIN_PLACE(k7, w7)
#undef BIN_PLACE
        __syncthreads();
        for (int i = tid; i < csz; i += NT)
            pairs[base + i] = stage[i];
    } else {
        int idx = (blockIdx.x - EB) * NT + threadIdx.x;
        if (idx < total4) elu_store(x, w, emb2, idx);
    }
}

// K2: one block per 32-row range. Coalesced read of loff rows r, r+1;
// collect ~512 pairs from EB small L2-resident segments; RSZ=32 LDS
// counting-sort; then ROW-INTERLEAVED register gather: per iteration issue
// 4 clamped loads from EACH of the wave's 4 rows (16 independent loads in
// flight) before accumulating -- attacks the R14 latency stall (VGPR=24
// showed only ~2-3 loads in flight).
__global__ __launch_bounds__(NT) void gather_kernel(
        const __half* __restrict__ emb2, const u32* __restrict__ pairs,
        const u32* __restrict__ loff, int EB, int NR, int E,
        float* __restrict__ out, int N) {
    __shared__ u32 lofA[NT];
    __shared__ u32 lofB[NT];
    __shared__ u32 coll[CAP];          // 8 KB
    __shared__ u16 sorted[CAP];        // 4 KB
    __shared__ u32 bcnt[RSZ + 1];
    __shared__ u32 bstart[RSZ + 1];
    __shared__ u32 ltot;
    int tid = threadIdx.x;
    int r = blockIdx.x;
    if (r >= NR) return;
    const int wv = tid >> 6;
    const int lane = tid & 63;
    if (tid < EB) {
        lofA[tid] = loff[(size_t)r * EB + tid];
        lofB[tid] = loff[(size_t)(r + 1) * EB + tid];
    }
    if (tid == 0) ltot = 0;
    if (tid < RSZ + 1) bcnt[tid] = 0;
    __syncthreads();
    if (tid < EB) {
        int cb = tid * EPB;
        u32 cmax = (u32)((E - cb) < EPB ? (E - cb) : EPB);
        u32 s = lofA[tid], e = lofB[tid];
        if (s > cmax) s = cmax;
        if (e > cmax) e = cmax;
        if (e < s) e = s;
        u32 n = e - s;
        if (n) {
            u32 off = atomicAdd(&ltot, n);
            for (u32 i = 0; i < n; ++i) {
                u32 p = off + i;
                if (p < (u32)CAP) coll[p] = pairs[(size_t)cb + s + i];
            }
        }
    }
    __syncthreads();
    u32 total = ltot;
    if (total > (u32)CAP) total = (u32)CAP;   // armor (astronomically unlikely)
    // counting-sort by local row (named slots: total <= CAP = 4*NT)
    u32 q0=~0u,q1=~0u,q2=~0u,q3=~0u;
    u32 s0=0,s1=0,s2=0,s3=0;
#define G_CNT(Q, M, V) { \
        u32 i = (u32)tid + Q * NT; \
        if (i < total) { \
            u32 pv = coll[i]; \
            u32 key = (pv >> 16) & (RSZ - 1u); \
            u32 rk = atomicAdd(&bcnt[key], 1u); \
            M = (key << 16) | (rk & 0xFFFFu); V = pv; \
        } }
    G_CNT(0u, q0, s0) G_CNT(1u, q1, s1) G_CNT(2u, q2, s2) G_CNT(3u, q3, s3)
#undef G_CNT
    __syncthreads();
    if (tid < RSZ) {
        u32 vv = bcnt[tid];
        u32 inc = vv;
        for (int d = 1; d < RSZ; d <<= 1) {
            u32 o = __shfl_up(inc, d);
            if (lane >= d) inc += o;
        }
        bstart[tid] = inc - vv;
        if (tid == RSZ - 1) bstart[RSZ] = inc;
    }
    __syncthreads();
#define G_PLACE(M, V) if (M != ~0u) { \
        u32 pos = bstart[M >> 16] + (M & 0xFFFFu); \
        sorted[pos & (CAP - 1u)] = (u16)(V & 0xFFFFu); }
    G_PLACE(q0, s0) G_PLACE(q1, s1) G_PLACE(q2, s2) G_PLACE(q3, s3)
#undef G_PLACE
    __syncthreads();
    float ax0 = 0.f, ay0 = 0.f, ax1 = 0.f, ay1 = 0.f;
    float ax2 = 0.f, ay2 = 0.f, ax3 = 0.f, ay3 = 0.f;
    {
        int rw = wv << 2;
        int jb0 = (int)bstart[rw],     je0 = (int)bstart[rw + 1];
        int jb1 = (int)bstart[rw + 1], je1 = (int)bstart[rw + 2];
        int jb2 = (int)bstart[rw + 2], je2 = (int)bstart[rw + 3];
        int jb3 = (int)bstart[rw + 3], je3 = (int)bstart[rw + 4];
        int l0 = je0 - jb0, l1 = je1 - jb1, l2 = je2 - jb2, l3 = je3 - jb3;
        int lmax = l0 > l1 ? l0 : l1;
        if (l2 > lmax) lmax = l2;
        if (l3 > lmax) lmax = l3;
        // clamp helper: valid LDS index even for exhausted/empty rows
#define CIDX(JB, JE, I) (((JB) + k + (I)) < (JE) ? ((JB) + k + (I)) : ((JE) > 0 ? (JE) - 1 : 0))
        for (int k = 0; k < lmax; k += 4) {
            // 16 sorted-LDS reads (independent)
            u32 e00 = (u32)sorted[CIDX(jb0, je0, 0)];
            u32 e01 = (u32)sorted[CIDX(jb0, je0, 1)];
            u32 e02 = (u32)sorted[CIDX(jb0, je0, 2)];
            u32 e03 = (u32)sorted[CIDX(jb0, je0, 3)];
            u32 e10 = (u32)sorted[CIDX(jb1, je1, 0)];
            u32 e11 = (u32)sorted[CIDX(jb1, je1, 1)];
            u32 e12 = (u32)sorted[CIDX(jb1, je1, 2)];
            u32 e13 = (u32)sorted[CIDX(jb1, je1, 3)];
            u32 e20 = (u32)sorted[CIDX(jb2, je2, 0)];
            u32 e21 = (u32)sorted[CIDX(jb2, je2, 1)];
            u32 e22 = (u32)sorted[CIDX(jb2, je2, 2)];
            u32 e23 = (u32)sorted[CIDX(jb2, je2, 3)];
            u32 e30 = (u32)sorted[CIDX(jb3, je3, 0)];
            u32 e31 = (u32)sorted[CIDX(jb3, je3, 1)];
            u32 e32 = (u32)sorted[CIDX(jb3, je3, 2)];
            u32 e33 = (u32)sorted[CIDX(jb3, je3, 3)];
            // 16 independent global row loads in flight
            u32 h00 = ((const u32*)(emb2 + (size_t)e00 * DFEAT))[lane];
            u32 h01 = ((const u32*)(emb2 + (size_t)e01 * DFEAT))[lane];
            u32 h02 = ((const u32*)(emb2 + (size_t)e02 * DFEAT))[lane];
            u32 h03 = ((const u32*)(emb2 + (size_t)e03 * DFEAT))[lane];
            u32 h10 = ((const u32*)(emb2 + (size_t)e10 * DFEAT))[lane];
            u32 h11 = ((const u32*)(emb2 + (size_t)e11 * DFEAT))[lane];
            u32 h12 = ((const u32*)(emb2 + (size_t)e12 * DFEAT))[lane];
            u32 h13 = ((const u32*)(emb2 + (size_t)e13 * DFEAT))[lane];
            u32 h20 = ((const u32*)(emb2 + (size_t)e20 * DFEAT))[lane];
            u32 h21 = ((const u32*)(emb2 + (size_t)e21 * DFEAT))[lane];
            u32 h22 = ((const u32*)(emb2 + (size_t)e22 * DFEAT))[lane];
            u32 h23v = ((const u32*)(emb2 + (size_t)e23 * DFEAT))[lane];
            u32 h30 = ((const u32*)(emb2 + (size_t)e30 * DFEAT))[lane];
            u32 h31 = ((const u32*)(emb2 + (size_t)e31 * DFEAT))[lane];
            u32 h32 = ((const u32*)(emb2 + (size_t)e32 * DFEAT))[lane];
            u32 h33 = ((const u32*)(emb2 + (size_t)e33 * DFEAT))[lane];
            // guarded accumulation per row
            if (k + 0 < l0) { float2 f = __half22float2(*(__half2*)&h00); ax0 += f.x; ay0 += f.y; }
            if (k + 1 < l0) { float2 f = __half22float2(*(__half2*)&h01); ax0 += f.x; ay0 += f.y; }
            if (k + 2 < l0) { float2 f = __half22float2(*(__half2*)&h02); ax0 += f.x; ay0 += f.y; }
            if (k + 3 < l0) { float2 f = __half22float2(*(__half2*)&h03); ax0 += f.x; ay0 += f.y; }
            if (k + 0 < l1) { float2 f = __half22float2(*(__half2*)&h10); ax1 += f.x; ay1 += f.y; }
            if (k + 1 < l1) { float2 f = __half22float2(*(__half2*)&h11); ax1 += f.x; ay1 += f.y; }
            if (k + 2 < l1) { float2 f = __half22float2(*(__half2*)&h12); ax1 += f.x; ay1 += f.y; }
            if (k + 3 < l1) { float2 f = __half22float2(*(__half2*)&h13); ax1 += f.x; ay1 += f.y; }
            if (k + 0 < l2) { float2 f = __half22float2(*(__half2*)&h20); ax2 += f.x; ay2 += f.y; }
            if (k + 1 < l2) { float2 f = __half22float2(*(__half2*)&h21); ax2 += f.x; ay2 += f.y; }
            if (k + 2 < l2) { float2 f = __half22float2(*(__half2*)&h22); ax2 += f.x; ay2 += f.y; }
            if (k + 3 < l2) { float2 f = __half22float2(*(__half2*)&h23v); ax2 += f.x; ay2 += f.y; }
            if (k + 0 < l3) { float2 f = __half22float2(*(__half2*)&h30); ax3 += f.x; ay3 += f.y; }
            if (k + 1 < l3) { float2 f = __half22float2(*(__half2*)&h31); ax3 += f.x; ay3 += f.y; }
            if (k + 2 < l3) { float2 f = __half22float2(*(__half2*)&h32); ax3 += f.x; ay3 += f.y; }
            if (k + 3 < l3) { float2 f = __half22float2(*(__half2*)&h33); ax3 += f.x; ay3 += f.y; }
        }
#undef CIDX
    }
    int nbase = (r << RSH) + (wv << 2);
    if (nbase + 0 < N) ((float2*)out)[(size_t)(nbase + 0) * (DFEAT / 2) + lane] = make_float2(ax0, ay0);
    if (nbase + 1 < N) ((float2*)out)[(size_t)(nbase + 1) * (DFEAT / 2) + lane] = make_float2(ax1, ay1);
    if (nbase + 2 < N) ((float2*)out)[(size_t)(nbase + 2) * (DFEAT / 2) + lane] = make_float2(ax2, ay2);
    if (nbase + 3 < N) ((float2*)out)[(size_t)(nbase + 3) * (DFEAT / 2) + lane] = make_float2(ax3, ay3);
}

// ---------------- fallback paths (unchanged) ----------------

__global__ void bin_elu_ll_kernel(const float* __restrict__ x,
                                  const float* __restrict__ w,
                                  __half* __restrict__ emb2, int total4,
                                  const int* __restrict__ src,
                                  const int* __restrict__ dst, int E,
                                  u64* __restrict__ head,
                                  u64* __restrict__ nxt,
                                  int binBlocks) {
    if ((int)blockIdx.x < binBlocks) {
        int base = blockIdx.x * 1024 + threadIdx.x;
        for (int q = 0; q < 4; ++q) {
            int e = base + q * 256;
            if (e < E) {
                int s = src[e];
                int d = dst[e];
                u64 old = atomicExch(&head[d], ((u64)(u32)s << 32) | (u32)e);
                nxt[e] = old;
            }
        }
    } else {
        int idx = (blockIdx.x - binBlocks) * blockDim.x + threadIdx.x;
        if (idx >= total4) return;
        elu_store(x, w, emb2, idx);
    }
}

__global__ void gather_ll_kernel(const __half* __restrict__ emb2,
                                 const u64* __restrict__ head,
                                 const u64* __restrict__ nxt,
                                 float* __restrict__ out, int N) {
    int wid = (blockIdx.x * blockDim.x + threadIdx.x) >> 6;
    int lane = threadIdx.x & 63;
    int nA = wid * 2;
    int nB = nA + 1;
    if (nA >= N) return;
    bool hasB = (nB < N);
    u64 curA = head[nA];
    u64 curB = hasB ? head[nB] : ENDK;
    float2 accA = make_float2(0.0f, 0.0f);
    float2 accB = make_float2(0.0f, 0.0f);
    while (curA != ENDK || curB != ENDK) {
        bool aA = (curA != ENDK);
        bool aB = (curB != ENDK);
        u64 cA = curA, cB = curB;
        u32 uA = 0, uB = 0;
        if (aA) uA = ((const u32*)(emb2 + ((size_t)(cA >> 32)) * DFEAT))[lane];
        if (aB) uB = ((const u32*)(emb2 + ((size_t)(cB >> 32)) * DFEAT))[lane];
        if (aA) curA = nxt[(u32)cA];
        if (aB) curB = nxt[(u32)cB];
        if (aA) {
            float2 f = __half22float2(*(__half2*)&uA);
            accA.x += f.x; accA.y += f.y;
        }
        if (aB) {
            float2 f = __half22float2(*(__half2*)&uB);
            accB.x += f.x; accB.y += f.y;
        }
    }
    ((float2*)(out + (size_t)nA * DFEAT))[lane] = accA;
    if (hasB) ((float2*)(out + (size_t)nB * DFEAT))[lane] = accB;
}

__global__ void scatter_fused_kernel(const float* __restrict__ x,
                                     const float* __restrict__ w,
                                     const int* __restrict__ src,
                                     const int* __restrict__ dst,
                                     float* __restrict__ out, int E) {
    int t = blockIdx.x * blockDim.x + threadIdx.x;
    int edge = t >> 5;
    int lane = t & 31;
    if (edge >= E) return;
    int s = src[edge];
    int d = dst[edge];
    float4 xv = ((const float4*)(x + (size_t)s * DFEAT))[lane];
    float4 wv = ((const float4*)w)[lane];
    float4 v;
    float a;
    a = xv.x * wv.x; v.x = 2.0f * (a > 0.0f ? a : (__expf(a) - 1.0f));
    a = xv.y * wv.y; v.y = 2.0f * (a > 0.0f ? a : (__expf(a) - 1.0f));
    a = xv.z * wv.z; v.z = 2.0f * (a > 0.0f ? a : (__expf(a) - 1.0f));
    a = xv.w * wv.w; v.w = 2.0f * (a > 0.0f ? a : (__expf(a) - 1.0f));
    float* op = out + (size_t)d * DFEAT + lane * 4;
    unsafeAtomicAdd(op + 0, v.x);
    unsafeAtomicAdd(op + 1, v.y);
    unsafeAtomicAdd(op + 2, v.z);
    unsafeAtomicAdd(op + 3, v.w);
}

extern "C" void kernel_launch(void* const* d_in, const int* in_sizes, int n_in,
                              void* d_out, int out_size, void* d_ws, size_t ws_size,
                              hipStream_t stream) {
    const float* x   = (const float*)d_in[0];   // graph_embedding [N, 128]
    const float* w   = (const float*)d_in[1];   // weight [1, 128]
    const int*   src = (const int*)d_in[3];     // src [E]
    const int*   dst = (const int*)d_in[4];     // dst [E]
    float* out = (float*)d_out;

    const int ND = in_sizes[0];          // N * 128
    const int N  = ND / DFEAT;           // 50000
    const int E  = in_sizes[2];          // 800000

    const int EB = (E + EPB - 1) / EPB;             // bin chunks (196)
    const int NR = (N + RSZ - 1) >> RSH;            // ranges (1563)

    size_t emb_bytes   = ((size_t)ND * sizeof(__half) + 15) & ~(size_t)15;        // 12.8 MB
    size_t pairs_bytes = ((size_t)E * sizeof(u32) + 15) & ~(size_t)15;            // 3.2 MB
    size_t loff_bytes  = ((size_t)(NR + 1) * EB * sizeof(u32) + 15) & ~(size_t)15; // ~1.2 MB
    size_t total_new = emb_bytes + pairs_bytes + loff_bytes;

    size_t head64_bytes = ((size_t)N * sizeof(u64) + 15) & ~(size_t)15;
    size_t nxt64_bytes  = ((size_t)E * sizeof(u64) + 15) & ~(size_t)15;
    size_t total_old = emb_bytes + head64_bytes + nxt64_bytes;

    int total4 = ND / 4;

    if (ws_size >= total_new && N <= 65536 && NR + 1 <= MAXR && EB <= NT) {
        char* p = (char*)d_ws;
        __half* emb2  = (__half*)p;  p += emb_bytes;
        u32*    pairs = (u32*)p;     p += pairs_bytes;
        u32*    loff  = (u32*)p;

        int eluBlocks = (total4 + NT - 1) / NT;
        bin_elu_kernel<<<EB + eluBlocks, NT, 0, stream>>>(
            x, w, emb2, total4, src, dst, E, pairs, loff, EB, NR);

        gather_kernel<<<NR, NT, 0, stream>>>(
            emb2, pairs, loff, EB, NR, E, out, N);
    } else if (ws_size >= total_old) {
        char* p = (char*)d_ws;
        __half* emb2 = (__half*)p;  p += emb_bytes;
        u64*    head = (u64*)p;     p += head64_bytes;
        u64*    nxt  = (u64*)p;

        hipMemsetAsync(head, 0xFF, (size_t)N * sizeof(u64), stream);

        int eluBlocks256 = (total4 + 255) / 256;
        int binBlocks = (E + 1023) / 1024;
        bin_elu_ll_kernel<<<binBlocks + eluBlocks256, 256, 0, stream>>>(
            x, w, emb2, total4, src, dst, E, head, nxt, binBlocks);

        long long waves = (N + 1) / 2;
        long long thr = waves * 64;
        gather_ll_kernel<<<(int)((thr + 255) / 256), 256, 0, stream>>>(
            emb2, head, nxt, out, N);
    } else {
        hipMemsetAsync(d_out, 0, (size_t)out_size * sizeof(float), stream);
        long long threads = (long long)E * 32;
        scatter_fused_kernel<<<(int)((threads + 255) / 256), 256, 0, stream>>>(x, w, src, dst, out, E);
    }
}

// Round 16
// 129.716 us; speedup vs baseline: 1.0628x; 1.0628x over previous
//
#include <hip/hip_runtime.h>
#include <hip/hip_fp16.h>
#include <math.h>

#define DFEAT 128
#define RSH 5            // log2(rows per range)
#define RSZ 32           // rows per range
#define MAXR 2048        // max ranges (N <= 65504)
#define NT  512          // threads per block
#define EPB 4096         // edges per bin chunk
#define CAP 2048         // gather collect capacity (range mean ~512)
typedef unsigned long long u64;
typedef unsigned int u32;
typedef unsigned short u16;
#define ENDK 0xFFFFFFFFFFFFFFFFULL

__device__ __forceinline__ void elu_store(const float* x, const float* w,
                                          __half* emb2, int i) {
    float4 xv = ((const float4*)x)[i];
    float4 wv = ((const float4*)w)[i & (DFEAT / 4 - 1)];
    float a, r0, r1, r2, r3;
    a = xv.x * wv.x; r0 = 2.0f * (a > 0.0f ? a : (__expf(a) - 1.0f));
    a = xv.y * wv.y; r1 = 2.0f * (a > 0.0f ? a : (__expf(a) - 1.0f));
    a = xv.z * wv.z; r2 = 2.0f * (a > 0.0f ? a : (__expf(a) - 1.0f));
    a = xv.w * wv.w; r3 = 2.0f * (a > 0.0f ? a : (__expf(a) - 1.0f));
    __half2 h01 = __floats2half2_rn(r0, r1);
    __half2 h23 = __floats2half2_rn(r2, r3);
    uint2 pk;
    pk.x = *(u32*)&h01;
    pk.y = *(u32*)&h23;
    ((uint2*)emb2)[i] = pk;
}

// K1: blocks [0,EB): chunk-local counting-sort of 4096 edges by range id
// (dst>>RSH). Zero global atomics. blocks [EB,..): elu -> emb2 fp16.
__global__ __launch_bounds__(NT) void bin_elu_kernel(
        const float* __restrict__ x, const float* __restrict__ w,
        __half* __restrict__ emb2, int total4,
        const int* __restrict__ src, const int* __restrict__ dst, int E,
        u32* __restrict__ pairs, u32* __restrict__ loff,
        int EB, int NR) {
    if ((int)blockIdx.x < EB) {
        __shared__ u32 cnt[MAXR];      // 8 KB: counts -> starts -> cursors
        __shared__ u32 sb[NT];         // 2 KB: scan partials
        __shared__ u32 stage[EPB];     // 16 KB: sorted staging
        int tid = threadIdx.x;
        int c = blockIdx.x;
        for (int i = tid; i < MAXR; i += NT) cnt[i] = 0;
        __syncthreads();
        int base = c * EPB;
        int csz = E - base; if (csz > EPB) csz = EPB;
        u32 k0=~0u,k1=~0u,k2=~0u,k3=~0u,k4=~0u,k5=~0u,k6=~0u,k7=~0u;
        u32 w0=0,w1=0,w2=0,w3=0,w4=0,w5=0,w6=0,w7=0;
#define BIN_LOAD(Q, K, W) { \
        int e = base + tid + Q * NT; \
        if (e < E) { \
            u32 d = (u32)dst[e]; \
            u32 s = (u32)src[e]; \
            u32 r = d >> RSH; if (r >= (u32)NR) r = (u32)NR - 1u; \
            atomicAdd(&cnt[r], 1u); \
            K = r; \
            W = ((d & (RSZ - 1u)) << 16) | (s & 0xFFFFu); \
        } }
        BIN_LOAD(0, k0, w0) BIN_LOAD(1, k1, w1) BIN_LOAD(2, k2, w2) BIN_LOAD(3, k3, w3)
        BIN_LOAD(4, k4, w4) BIN_LOAD(5, k5, w5) BIN_LOAD(6, k6, w6) BIN_LOAD(7, k7, w7)
#undef BIN_LOAD
        __syncthreads();
        u32 c0 = cnt[4 * tid], c1 = cnt[4 * tid + 1];
        u32 c2 = cnt[4 * tid + 2], c3 = cnt[4 * tid + 3];
        sb[tid] = c0 + c1 + c2 + c3;
        __syncthreads();
        for (int d = 1; d < NT; d <<= 1) {
            u32 o = (tid >= d) ? sb[tid - d] : 0u;
            __syncthreads();
            sb[tid] += o;
            __syncthreads();
        }
        u32 excl = sb[tid] - (c0 + c1 + c2 + c3);
        cnt[4 * tid]     = excl;
        cnt[4 * tid + 1] = excl + c0;
        cnt[4 * tid + 2] = excl + c0 + c1;
        cnt[4 * tid + 3] = excl + c0 + c1 + c2;
        __syncthreads();
        for (int r = tid; r < NR; r += NT)
            loff[(size_t)r * EB + c] = cnt[r];
        if (tid == 0) loff[(size_t)NR * EB + c] = (u32)csz;
        __syncthreads();
#define BIN_PLACE(K, W) if (K != ~0u) { \
        u32 p = atomicAdd(&cnt[K], 1u); \
        stage[p & (EPB - 1u)] = W; }
        BIN_PLACE(k0, w0) BIN_PLACE(k1, w1) BIN_PLACE(k2, w2) BIN_PLACE(k3, w3)
        BIN_PLACE(k4, w4) BIN_PLACE(k5, w5) BIN_PLACE(k6, w6) BIN_PLACE(k7, w7)
#undef BIN_PLACE
        __syncthreads();
        for (int i = tid; i < csz; i += NT)
            pairs[base + i] = stage[i];
    } else {
        int idx = (blockIdx.x - EB) * NT + threadIdx.x;
        if (idx < total4) elu_store(x, w, emb2, idx);
    }
}

// K2: one block per 32-row range. Collect from per-chunk segments; RSZ=32
// LDS counting-sort; then 2-ROWS-PER-LOAD register gather: lanes 0-31 serve
// one row, lanes 32-63 the other (uint2/lane -> 512 B per load instruction,
// HALF the L1/TA request count of one-row-per-load). 8 loads in flight.
// float4 writeout per half-wave.
__global__ __launch_bounds__(NT) void gather_kernel(
        const __half* __restrict__ emb2, const u32* __restrict__ pairs,
        const u32* __restrict__ loff, int EB, int NR, int E,
        float* __restrict__ out, int N) {
    __shared__ u32 lofA[NT];
    __shared__ u32 lofB[NT];
    __shared__ u32 coll[CAP];          // 8 KB
    __shared__ u16 sorted[CAP];        // 4 KB
    __shared__ u32 bcnt[RSZ + 1];
    __shared__ u32 bstart[RSZ + 1];
    __shared__ u32 ltot;
    int tid = threadIdx.x;
    int r = blockIdx.x;
    if (r >= NR) return;
    const int wv = tid >> 6;
    const int lane = tid & 63;
    if (tid < EB) {
        lofA[tid] = loff[(size_t)r * EB + tid];
        lofB[tid] = loff[(size_t)(r + 1) * EB + tid];
    }
    if (tid == 0) ltot = 0;
    if (tid < RSZ + 1) bcnt[tid] = 0;
    __syncthreads();
    if (tid < EB) {
        int cb = tid * EPB;
        u32 cmax = (u32)((E - cb) < EPB ? (E - cb) : EPB);
        u32 s = lofA[tid], e = lofB[tid];
        if (s > cmax) s = cmax;
        if (e > cmax) e = cmax;
        if (e < s) e = s;
        u32 n = e - s;
        if (n) {
            u32 off = atomicAdd(&ltot, n);
            for (u32 i = 0; i < n; ++i) {
                u32 p = off + i;
                if (p < (u32)CAP) coll[p] = pairs[(size_t)cb + s + i];
            }
        }
    }
    __syncthreads();
    u32 total = ltot;
    if (total > (u32)CAP) total = (u32)CAP;   // armor
    u32 q0=~0u,q1=~0u,q2=~0u,q3=~0u;
    u32 s0=0,s1=0,s2=0,s3=0;
#define G_CNT(Q, M, V) { \
        u32 i = (u32)tid + Q * NT; \
        if (i < total) { \
            u32 pv = coll[i]; \
            u32 key = (pv >> 16) & (RSZ - 1u); \
            u32 rk = atomicAdd(&bcnt[key], 1u); \
            M = (key << 16) | (rk & 0xFFFFu); V = pv; \
        } }
    G_CNT(0u, q0, s0) G_CNT(1u, q1, s1) G_CNT(2u, q2, s2) G_CNT(3u, q3, s3)
#undef G_CNT
    __syncthreads();
    if (tid < RSZ) {
        u32 vv = bcnt[tid];
        u32 inc = vv;
        for (int d = 1; d < RSZ; d <<= 1) {
            u32 o = __shfl_up(inc, d);
            if (lane >= d) inc += o;
        }
        bstart[tid] = inc - vv;
        if (tid == RSZ - 1) bstart[RSZ] = inc;
    }
    __syncthreads();
#define G_PLACE(M, V) if (M != ~0u) { \
        u32 pos = bstart[M >> 16] + (M & 0xFFFFu); \
        sorted[pos & (CAP - 1u)] = (u16)(V & 0xFFFFu); }
    G_PLACE(q0, s0) G_PLACE(q1, s1) G_PLACE(q2, s2) G_PLACE(q3, s3)
#undef G_PLACE
    __syncthreads();
    // ---- 2-rows-per-load gather ----
    const int h = lane >> 5;           // which row of the pair this half serves
    const int sub = lane & 31;         // uint2 column (4 halves) within the row
    const int rw = wv << 2;
#define G_PAIR(P) { \
        int rowIdx = rw + 2 * P + h; \
        int jb = (int)bstart[rowIdx], je = (int)bstart[rowIdx + 1]; \
        int len = je - jb; \
        int lA = (int)bstart[rw + 2 * P + 1] - (int)bstart[rw + 2 * P]; \
        int lB = (int)bstart[rw + 2 * P + 2] - (int)bstart[rw + 2 * P + 1]; \
        int lmax = lA > lB ? lA : lB; \
        float a0 = 0.f, a1 = 0.f, a2 = 0.f, a3 = 0.f; \
        int last = je > 0 ? je - 1 : 0; \
        for (int k = 0; k < lmax; k += 8) { \
            int i0 = jb + k     < je ? jb + k     : last; \
            int i1 = jb + k + 1 < je ? jb + k + 1 : last; \
            int i2 = jb + k + 2 < je ? jb + k + 2 : last; \
            int i3 = jb + k + 3 < je ? jb + k + 3 : last; \
            int i4 = jb + k + 4 < je ? jb + k + 4 : last; \
            int i5 = jb + k + 5 < je ? jb + k + 5 : last; \
            int i6 = jb + k + 6 < je ? jb + k + 6 : last; \
            int i7 = jb + k + 7 < je ? jb + k + 7 : last; \
            u32 e0 = (u32)sorted[i0]; u32 e1 = (u32)sorted[i1]; \
            u32 e2 = (u32)sorted[i2]; u32 e3 = (u32)sorted[i3]; \
            u32 e4 = (u32)sorted[i4]; u32 e5 = (u32)sorted[i5]; \
            u32 e6 = (u32)sorted[i6]; u32 e7 = (u32)sorted[i7]; \
            uint2 g0 = ((const uint2*)(emb2 + (size_t)e0 * DFEAT))[sub]; \
            uint2 g1 = ((const uint2*)(emb2 + (size_t)e1 * DFEAT))[sub]; \
            uint2 g2 = ((const uint2*)(emb2 + (size_t)e2 * DFEAT))[sub]; \
            uint2 g3 = ((const uint2*)(emb2 + (size_t)e3 * DFEAT))[sub]; \
            uint2 g4 = ((const uint2*)(emb2 + (size_t)e4 * DFEAT))[sub]; \
            uint2 g5 = ((const uint2*)(emb2 + (size_t)e5 * DFEAT))[sub]; \
            uint2 g6 = ((const uint2*)(emb2 + (size_t)e6 * DFEAT))[sub]; \
            uint2 g7 = ((const uint2*)(emb2 + (size_t)e7 * DFEAT))[sub]; \
            if (k     < len) { float2 fl = __half22float2(*(__half2*)&g0.x); float2 fh = __half22float2(*(__half2*)&g0.y); a0 += fl.x; a1 += fl.y; a2 += fh.x; a3 += fh.y; } \
            if (k + 1 < len) { float2 fl = __half22float2(*(__half2*)&g1.x); float2 fh = __half22float2(*(__half2*)&g1.y); a0 += fl.x; a1 += fl.y; a2 += fh.x; a3 += fh.y; } \
            if (k + 2 < len) { float2 fl = __half22float2(*(__half2*)&g2.x); float2 fh = __half22float2(*(__half2*)&g2.y); a0 += fl.x; a1 += fl.y; a2 += fh.x; a3 += fh.y; } \
            if (k + 3 < len) { float2 fl = __half22float2(*(__half2*)&g3.x); float2 fh = __half22float2(*(__half2*)&g3.y); a0 += fl.x; a1 += fl.y; a2 += fh.x; a3 += fh.y; } \
            if (k + 4 < len) { float2 fl = __half22float2(*(__half2*)&g4.x); float2 fh = __half22float2(*(__half2*)&g4.y); a0 += fl.x; a1 += fl.y; a2 += fh.x; a3 += fh.y; } \
            if (k + 5 < len) { float2 fl = __half22float2(*(__half2*)&g5.x); float2 fh = __half22float2(*(__half2*)&g5.y); a0 += fl.x; a1 += fl.y; a2 += fh.x; a3 += fh.y; } \
            if (k + 6 < len) { float2 fl = __half22float2(*(__half2*)&g6.x); float2 fh = __half22float2(*(__half2*)&g6.y); a0 += fl.x; a1 += fl.y; a2 += fh.x; a3 += fh.y; } \
            if (k + 7 < len) { float2 fl = __half22float2(*(__half2*)&g7.x); float2 fh = __half22float2(*(__half2*)&g7.y); a0 += fl.x; a1 += fl.y; a2 += fh.x; a3 += fh.y; } \
        } \
        int n = (r << RSH) + rowIdx; \
        if (n < N) ((float4*)out)[(size_t)n * (DFEAT / 4) + sub] = make_float4(a0, a1, a2, a3); \
    }
    G_PAIR(0)
    G_PAIR(1)
#undef G_PAIR
}

// ---------------- fallback paths (unchanged) ----------------

__global__ void bin_elu_ll_kernel(const float* __restrict__ x,
                                  const float* __restrict__ w,
                                  __half* __restrict__ emb2, int total4,
                                  const int* __restrict__ src,
                                  const int* __restrict__ dst, int E,
                                  u64* __restrict__ head,
                                  u64* __restrict__ nxt,
                                  int binBlocks) {
    if ((int)blockIdx.x < binBlocks) {
        int base = blockIdx.x * 1024 + threadIdx.x;
        for (int q = 0; q < 4; ++q) {
            int e = base + q * 256;
            if (e < E) {
                int s = src[e];
                int d = dst[e];
                u64 old = atomicExch(&head[d], ((u64)(u32)s << 32) | (u32)e);
                nxt[e] = old;
            }
        }
    } else {
        int idx = (blockIdx.x - binBlocks) * blockDim.x + threadIdx.x;
        if (idx >= total4) return;
        elu_store(x, w, emb2, idx);
    }
}

__global__ void gather_ll_kernel(const __half* __restrict__ emb2,
                                 const u64* __restrict__ head,
                                 const u64* __restrict__ nxt,
                                 float* __restrict__ out, int N) {
    int wid = (blockIdx.x * blockDim.x + threadIdx.x) >> 6;
    int lane = threadIdx.x & 63;
    int nA = wid * 2;
    int nB = nA + 1;
    if (nA >= N) return;
    bool hasB = (nB < N);
    u64 curA = head[nA];
    u64 curB = hasB ? head[nB] : ENDK;
    float2 accA = make_float2(0.0f, 0.0f);
    float2 accB = make_float2(0.0f, 0.0f);
    while (curA != ENDK || curB != ENDK) {
        bool aA = (curA != ENDK);
        bool aB = (curB != ENDK);
        u64 cA = curA, cB = curB;
        u32 uA = 0, uB = 0;
        if (aA) uA = ((const u32*)(emb2 + ((size_t)(cA >> 32)) * DFEAT))[lane];
        if (aB) uB = ((const u32*)(emb2 + ((size_t)(cB >> 32)) * DFEAT))[lane];
        if (aA) curA = nxt[(u32)cA];
        if (aB) curB = nxt[(u32)cB];
        if (aA) {
            float2 f = __half22float2(*(__half2*)&uA);
            accA.x += f.x; accA.y += f.y;
        }
        if (aB) {
            float2 f = __half22float2(*(__half2*)&uB);
            accB.x += f.x; accB.y += f.y;
        }
    }
    ((float2*)(out + (size_t)nA * DFEAT))[lane] = accA;
    if (hasB) ((float2*)(out + (size_t)nB * DFEAT))[lane] = accB;
}

__global__ void scatter_fused_kernel(const float* __restrict__ x,
                                     const float* __restrict__ w,
                                     const int* __restrict__ src,
                                     const int* __restrict__ dst,
                                     float* __restrict__ out, int E) {
    int t = blockIdx.x * blockDim.x + threadIdx.x;
    int edge = t >> 5;
    int lane = t & 31;
    if (edge >= E) return;
    int s = src[edge];
    int d = dst[edge];
    float4 xv = ((const float4*)(x + (size_t)s * DFEAT))[lane];
    float4 wv = ((const float4*)w)[lane];
    float4 v;
    float a;
    a = xv.x * wv.x; v.x = 2.0f * (a > 0.0f ? a : (__expf(a) - 1.0f));
    a = xv.y * wv.y; v.y = 2.0f * (a > 0.0f ? a : (__expf(a) - 1.0f));
    a = xv.z * wv.z; v.z = 2.0f * (a > 0.0f ? a : (__expf(a) - 1.0f));
    a = xv.w * wv.w; v.w = 2.0f * (a > 0.0f ? a : (__expf(a) - 1.0f));
    float* op = out + (size_t)d * DFEAT + lane * 4;
    unsafeAtomicAdd(op + 0, v.x);
    unsafeAtomicAdd(op + 1, v.y);
    unsafeAtomicAdd(op + 2, v.z);
    unsafeAtomicAdd(op + 3, v.w);
}

extern "C" void kernel_launch(void* const* d_in, const int* in_sizes, int n_in,
                              void* d_out, int out_size, void* d_ws, size_t ws_size,
                              hipStream_t stream) {
    const float* x   = (const float*)d_in[0];   // graph_embedding [N, 128]
    const float* w   = (const float*)d_in[1];   // weight [1, 128]
    const int*   src = (const int*)d_in[3];     // src [E]
    const int*   dst = (const int*)d_in[4];     // dst [E]
    float* out = (float*)d_out;

    const int ND = in_sizes[0];          // N * 128
    const int N  = ND / DFEAT;           // 50000
    const int E  = in_sizes[2];          // 800000

    const int EB = (E + EPB - 1) / EPB;             // bin chunks (196)
    const int NR = (N + RSZ - 1) >> RSH;            // ranges (1563)

    size_t emb_bytes   = ((size_t)ND * sizeof(__half) + 15) & ~(size_t)15;        // 12.8 MB
    size_t pairs_bytes = ((size_t)E * sizeof(u32) + 15) & ~(size_t)15;            // 3.2 MB
    size_t loff_bytes  = ((size_t)(NR + 1) * EB * sizeof(u32) + 15) & ~(size_t)15; // ~1.2 MB
    size_t total_new = emb_bytes + pairs_bytes + loff_bytes;

    size_t head64_bytes = ((size_t)N * sizeof(u64) + 15) & ~(size_t)15;
    size_t nxt64_bytes  = ((size_t)E * sizeof(u64) + 15) & ~(size_t)15;
    size_t total_old = emb_bytes + head64_bytes + nxt64_bytes;

    int total4 = ND / 4;

    if (ws_size >= total_new && N <= 65536 && NR + 1 <= MAXR && EB <= NT) {
        char* p = (char*)d_ws;
        __half* emb2  = (__half*)p;  p += emb_bytes;
        u32*    pairs = (u32*)p;     p += pairs_bytes;
        u32*    loff  = (u32*)p;

        int eluBlocks = (total4 + NT - 1) / NT;
        bin_elu_kernel<<<EB + eluBlocks, NT, 0, stream>>>(
            x, w, emb2, total4, src, dst, E, pairs, loff, EB, NR);

        gather_kernel<<<NR, NT, 0, stream>>>(
            emb2, pairs, loff, EB, NR, E, out, N);
    } else if (ws_size >= total_old) {
        char* p = (char*)d_ws;
        __half* emb2 = (__half*)p;  p += emb_bytes;
        u64*    head = (u64*)p;     p += head64_bytes;
        u64*    nxt  = (u64*)p;

        hipMemsetAsync(head, 0xFF, (size_t)N * sizeof(u64), stream);

        int eluBlocks256 = (total4 + 255) / 256;
        int binBlocks = (E + 1023) / 1024;
        bin_elu_ll_kernel<<<binBlocks + eluBlocks256, 256, 0, stream>>>(
            x, w, emb2, total4, src, dst, E, head, nxt, binBlocks);

        long long waves = (N + 1) / 2;
        long long thr = waves * 64;
        gather_ll_kernel<<<(int)((thr + 255) / 256), 256, 0, stream>>>(
            emb2, head, nxt, out, N);
    } else {
        hipMemsetAsync(d_out, 0, (size_t)out_size * sizeof(float), stream);
        long long threads = (long long)E * 32;
        scatter_fused_kernel<<<(int)((threads + 255) / 256), 256, 0, stream>>>(x, w, src, dst, out, E);
    }
}